// Round 8
// baseline (716.064 us; speedup 1.0000x reference)
//
#include <hip/hip_runtime.h>

using u16   = unsigned short;
using s16x8 = __attribute__((ext_vector_type(8))) short;          // 8 bf16 (4 VGPRs)
using u16x8 = __attribute__((ext_vector_type(8))) unsigned short;
using f32x4 = __attribute__((ext_vector_type(4))) float;

// fp32 -> bf16 round-to-nearest-even (bit math, deterministic)
__device__ __forceinline__ u16 f2bf(float f) {
    unsigned u = __float_as_uint(f);
    u += 0x7FFFu + ((u >> 16) & 1u);
    return (u16)(u >> 16);
}

// async global->LDS, 16B per lane; LDS dest must be wave-uniform base + lane*16
__device__ __forceinline__ void gload16(const void* g, void* l) {
    __builtin_amdgcn_global_load_lds((const __attribute__((address_space(1))) void*)g,
                                     (__attribute__((address_space(3))) void*)l, 16, 0, 0);
}

#define MFMA_BF16(a, b, d) \
    d = __builtin_amdgcn_mfma_f32_16x16x32_bf16(a, b, d, 0, 0, 0)

// ---------------------------------------------------------------------------
// 256x256 GEMM core, m201-faithful 4-quadrant schedule (T2+T3+T4+T5):
// C[256,256] += A[256,K] * Bt[256,K]^T. 512 threads = 8 waves (2M x 4N);
// per-wave 128x64 output = acc[8][4] f32x4. BK=64; LDS = 2 x 64 KiB dbuf,
// XOR-swizzled (byte ^= (row&7)<<4): linear gload_lds dest + pre-swizzled
// global source col + same XOR on ds_read addr (rule #21, both-sides).
//
// Phase pattern (m201 template): {ds_read this phase's fragments BEFORE the
// barrier} -> s_barrier -> lgkmcnt(0)+sched_barrier -> setprio(1) -> 16 MFMA
// -> setprio(0) -> s_barrier. ds_read latency overlaps the previous phase's
// MFMA tail; after the barrier the MFMA pipe starts immediately.
//
// Staging (counted vmcnt, never 0 mid-loop): prologue stages tiles 0 AND 1
// (16 loads in flight); iter t>=1 issues ALL 8 of tile t+1 at P1 (that LDS
// buffer's reads completed in iter t-1). Issue order A0,A2,B0..B3,A1,A3.
// Waits (traced): prologue vmcnt(10); per-iter vmcnt(8) after Q2 (tile t's
// A1,A3 - 7 phases cover) and vmcnt(2) after Q4 (tile t+1's first 6 - 3.5
// phases); last iter: vmcnt(0) after Q2, skip after Q4. Each wait precedes
// the barrier before the dependent ds_reads (cross-wave LDS visibility).
// ---------------------------------------------------------------------------
__device__ __forceinline__ void gemm256_core(
    const u16* __restrict__ A, const u16* __restrict__ Bt,
    int lda, int ldb, int kSteps, u16* lds, f32x4 (&acc)[8][4])
{
    const int tid  = threadIdx.x;
    const int lane = tid & 63;
    const int wid  = tid >> 6;
    const int wr   = wid >> 2;      // 0..1  (M half)
    const int wc   = wid & 3;       // 0..3  (N quarter)
    const int c    = lane & 15;
    const int g    = lane >> 4;

    // staging: thread t -> physical LDS sweep s: s*8192B + tid*16B (linear).
    // logical element = physical ^ ((row&7)<<4) => fetch global at swizzled col
    const int srow = tid >> 3;                               // row in 64-row sweep
    const int scol = ((tid & 7) * 8) ^ ((srow & 7) << 3);    // u16 units
    const u16* pA0 = A  + (size_t)srow * lda + scol;
    const u16* pB0 = Bt + (size_t)srow * ldb + scol;
    const size_t sA = (size_t)64 * lda;
    const size_t sB = (size_t)64 * ldb;
    const int ldst = tid * 8;                                // u16 within segment

    // read-side offsets (swizzle folds to lane-constant XOR)
    const int low0 = (g * 8)      ^ ((c & 7) << 3);          // kk=0, u16 units
    const int low1 = (32 + g * 8) ^ ((c & 7) << 3);          // kk=1
    const int aRow = (wr * 128 + c) * 64;                    // + m*1024
    const int bRow = (wc * 64 + c) * 64;                     // + n*1024

#define STAGE8(buf, qa, qb)                                    \
    do {                                                       \
        u16* wA_ = (buf);                                      \
        u16* wB_ = (buf) + 16384;                              \
        gload16((qa) + 0 * sA, wA_ + 0 * 4096 + ldst);         \
        gload16((qa) + 2 * sA, wA_ + 2 * 4096 + ldst);         \
        gload16((qb) + 0 * sB, wB_ + 0 * 4096 + ldst);         \
        gload16((qb) + 1 * sB, wB_ + 1 * 4096 + ldst);         \
        gload16((qb) + 2 * sB, wB_ + 2 * 4096 + ldst);         \
        gload16((qb) + 3 * sB, wB_ + 3 * 4096 + ldst);         \
        gload16((qa) + 1 * sA, wA_ + 1 * 4096 + ldst);         \
        gload16((qa) + 3 * sA, wA_ + 3 * 4096 + ldst);         \
    } while (0)

    // prologue: stage tile0 -> buf0 and tile1 -> buf1 (both buffers free)
    STAGE8(lds, pA0, pB0);
    if (kSteps > 1) STAGE8(lds + 32768, pA0 + 64, pB0 + 64);
    const u16* pA = pA0 + 128;   // column of tile 2 (first in-loop stage)
    const u16* pB = pB0 + 128;

    if (kSteps > 1) asm volatile("s_waitcnt vmcnt(10)" ::: "memory");
    else            asm volatile("s_waitcnt vmcnt(2)"  ::: "memory");
    __builtin_amdgcn_s_barrier();

    for (int t = 0; t < kSteps; ++t) {
        const u16* rdA = lds + (t & 1) * 32768;
        const u16* rdB = rdA + 16384;
        u16* wbuf = lds + ((t & 1) ^ 1) * 32768;
        const bool doStage = (t >= 1) && (t + 1 < kSteps);
        const bool last = (t + 1 == kSteps);

        s16x8 av[4][2], aw[4][2], bv[2][2], bw[2][2];

        // ---- P1: issue tile t+1 (8 gloads); ds_read av_lo + bv; MFMA Q1 ----
        if (doStage) { STAGE8(wbuf, pA, pB); pA += 64; pB += 64; }
#pragma unroll
        for (int m = 0; m < 4; ++m) {
            av[m][0] = *(const s16x8*)(rdA + aRow + m * 1024 + low0);
            av[m][1] = *(const s16x8*)(rdA + aRow + m * 1024 + low1);
        }
#pragma unroll
        for (int n = 0; n < 2; ++n) {
            bv[n][0] = *(const s16x8*)(rdB + bRow + n * 1024 + low0);
            bv[n][1] = *(const s16x8*)(rdB + bRow + n * 1024 + low1);
        }
        __builtin_amdgcn_s_barrier();
        asm volatile("s_waitcnt lgkmcnt(0)" ::: "memory");
        __builtin_amdgcn_sched_barrier(0);
        __builtin_amdgcn_s_setprio(1);
#pragma unroll
        for (int m = 0; m < 4; ++m)
#pragma unroll
            for (int n = 0; n < 2; ++n) {
                MFMA_BF16(av[m][0], bv[n][0], acc[m][n]);
                MFMA_BF16(av[m][1], bv[n][1], acc[m][n]);
            }
        __builtin_amdgcn_s_setprio(0);
        __builtin_amdgcn_s_barrier();

        // ---- P2: ds_read bw; MFMA Q2; then drain tile t's A1,A3 ----
#pragma unroll
        for (int n = 0; n < 2; ++n) {
            bw[n][0] = *(const s16x8*)(rdB + bRow + (n + 2) * 1024 + low0);
            bw[n][1] = *(const s16x8*)(rdB + bRow + (n + 2) * 1024 + low1);
        }
        __builtin_amdgcn_s_barrier();
        asm volatile("s_waitcnt lgkmcnt(0)" ::: "memory");
        __builtin_amdgcn_sched_barrier(0);
        __builtin_amdgcn_s_setprio(1);
#pragma unroll
        for (int m = 0; m < 4; ++m)
#pragma unroll
            for (int n = 0; n < 2; ++n) {
                MFMA_BF16(av[m][0], bw[n][0], acc[m][n + 2]);
                MFMA_BF16(av[m][1], bw[n][1], acc[m][n + 2]);
            }
        __builtin_amdgcn_s_setprio(0);
        if (last) asm volatile("s_waitcnt vmcnt(0)" ::: "memory");
        else      asm volatile("s_waitcnt vmcnt(8)" ::: "memory");
        __builtin_amdgcn_s_barrier();

        // ---- P3: ds_read av_hi (sweeps A1,A3); MFMA Q3 ----
#pragma unroll
        for (int m = 0; m < 4; ++m) {
            aw[m][0] = *(const s16x8*)(rdA + aRow + (m + 4) * 1024 + low0);
            aw[m][1] = *(const s16x8*)(rdA + aRow + (m + 4) * 1024 + low1);
        }
        __builtin_amdgcn_s_barrier();
        asm volatile("s_waitcnt lgkmcnt(0)" ::: "memory");
        __builtin_amdgcn_sched_barrier(0);
        __builtin_amdgcn_s_setprio(1);
#pragma unroll
        for (int m = 0; m < 4; ++m)
#pragma unroll
            for (int n = 0; n < 2; ++n) {
                MFMA_BF16(aw[m][0], bw[n][0], acc[m + 4][n + 2]);
                MFMA_BF16(aw[m][1], bw[n][1], acc[m + 4][n + 2]);
            }
        __builtin_amdgcn_s_setprio(0);
        __builtin_amdgcn_s_barrier();

        // ---- P4: MFMA Q4; then drain tile t+1's first 6 for next P1 ----
        __builtin_amdgcn_s_setprio(1);
#pragma unroll
        for (int m = 0; m < 4; ++m)
#pragma unroll
            for (int n = 0; n < 2; ++n) {
                MFMA_BF16(aw[m][0], bv[n][0], acc[m + 4][n]);
                MFMA_BF16(aw[m][1], bv[n][1], acc[m + 4][n]);
            }
        __builtin_amdgcn_s_setprio(0);
        if (!last) asm volatile("s_waitcnt vmcnt(2)" ::: "memory");
        __builtin_amdgcn_s_barrier();
    }
#undef STAGE8
}

// bijective XCD swizzle (requires nwg % 8 == 0; all our grids satisfy this)
__device__ __forceinline__ int xcd_swz(int bid, int nwg) {
    return (bid & 7) * (nwg >> 3) + (bid >> 3);
}

// ---------------------------------------------------------------------------
// 256-tile GEMM, bf16 output (Tm, Vt). grid.x = (M/256)*(N/256), grid.z = batch
// ---------------------------------------------------------------------------
__global__ __launch_bounds__(512, 2) void gemm256_bf16(
    const u16* __restrict__ A, const u16* __restrict__ Bt, u16* __restrict__ C,
    int N, int K, long aBatch, long bBatch, long cBatch)
{
    __shared__ u16 lds[65536];
    const int bid = xcd_swz((int)blockIdx.x, (int)gridDim.x);
    const int nT = N >> 8;
    const int m0 = (bid / nT) << 8;
    const int n0 = (bid % nT) << 8;
    const int b  = blockIdx.z;
    const u16* Ab = A  + (size_t)b * aBatch + (size_t)m0 * K;
    const u16* Bb = Bt + (size_t)b * bBatch + (size_t)n0 * K;
    f32x4 acc[8][4] = {};
    gemm256_core(Ab, Bb, K, K, K >> 6, lds, acc);

    u16* Cb = C + (size_t)b * cBatch;
    const int lane = threadIdx.x & 63;
    const int c = lane & 15, g = lane >> 4;
    const int wid = threadIdx.x >> 6;
    const int rowb = m0 + (wid >> 2) * 128 + g * 4;
    const int colb = n0 + (wid & 3) * 64 + c;
#pragma unroll
    for (int m = 0; m < 8; ++m)
#pragma unroll
        for (int n = 0; n < 4; ++n)
#pragma unroll
            for (int r = 0; r < 4; ++r)
                Cb[(size_t)(rowb + m * 16 + r) * N + colb + n * 16] = f2bf(acc[m][n][r]);
}

// ---------------------------------------------------------------------------
// attn_score 256: P~ = exp(scale * t . x^T) on causal lower-triangle 256-tiles;
// row sums via shfl reduce + atomicAdd. grid.x = 136, grid.z = batch.
// ---------------------------------------------------------------------------
__global__ __launch_bounds__(512, 2) void attn_score256(
    const u16* __restrict__ Tm, const u16* __restrict__ Xb,
    u16* __restrict__ P, float* __restrict__ L, long pStride, int bBase)
{
    __shared__ u16 lds[65536];
    const int b  = bBase + blockIdx.z;
    const int wg = xcd_swz((int)blockIdx.x, (int)gridDim.x);   // 136 = 8*17
    int it = (int)((sqrtf(8.0f * (float)wg + 1.0f) - 1.0f) * 0.5f);
    while ((it + 1) * (it + 2) / 2 <= wg) ++it;
    while (it * (it + 1) / 2 > wg) --it;
    const int jt = wg - it * (it + 1) / 2;
    const int i0 = it << 8, j0 = jt << 8;

    const u16* Ab = Tm + ((size_t)b * 4096 + i0) * 2048;
    const u16* Bb = Xb + ((size_t)b * 4096 + j0) * 2048;
    f32x4 acc[8][4] = {};
    gemm256_core(Ab, Bb, 2048, 2048, 32, lds, acc);

    u16*   Pb = P + (size_t)blockIdx.z * pStride;
    float* Lb = L + (size_t)b * 4096;
    const int lane = threadIdx.x & 63;
    const int c = lane & 15, g = lane >> 4;
    const int wid = threadIdx.x >> 6;
    const int rowb = i0 + (wid >> 2) * 128 + g * 4;
    const int colb = j0 + (wid & 3) * 64 + c;
    const float SCALE = 0.022097086912079608f;   // 1/sqrt(2048)

    float rsum[8][4];
#pragma unroll
    for (int m = 0; m < 8; ++m)
#pragma unroll
        for (int r = 0; r < 4; ++r) rsum[m][r] = 0.0f;
#pragma unroll
    for (int m = 0; m < 8; ++m) {
#pragma unroll
        for (int r = 0; r < 4; ++r) {
            const int Ig = rowb + m * 16 + r;
#pragma unroll
            for (int n = 0; n < 4; ++n) {
                const int Jg = colb + n * 16;
                // scaled scores ~N(0,0.82^2) => unnormalized exp is safe
                float p = (Jg > Ig) ? 0.0f : __expf(acc[m][n][r] * SCALE);
                Pb[(size_t)Ig * 4096 + Jg] = f2bf(p);
                rsum[m][r] += p;
            }
        }
    }
    // reduce across the 16 c-lanes (masks <16 stay within the g-group = same rows)
#pragma unroll
    for (int m = 0; m < 8; ++m)
#pragma unroll
        for (int r = 0; r < 4; ++r) {
            float v = rsum[m][r];
            v += __shfl_xor(v, 1);
            v += __shfl_xor(v, 2);
            v += __shfl_xor(v, 4);
            v += __shfl_xor(v, 8);
            rsum[m][r] = v;
        }
    if (c == 0) {
#pragma unroll
        for (int m = 0; m < 8; ++m)
#pragma unroll
            for (int r = 0; r < 4; ++r)
                atomicAdd(&Lb[rowb + m * 16 + r], rsum[m][r]);
    }
}

// ---------------------------------------------------------------------------
// attn_pv 256: O = (P~ @ V)/l over causal K-range; f32 output.
// Flat grid with explicit balance map: d = r*(64*zCount) + s*8 + x.
//   x = d&7 (~XCD), r = round, s -> (nt, z). it = r ? x : 15-x.
// Each CU gets it and 15-it across its two rounds => uniform 68 K-steps/CU;
// the 8 nt-blocks sharing a P i-strip land on one XCD (L2 locality).
// ---------------------------------------------------------------------------
__global__ __launch_bounds__(512, 2) void attn_pv256(
    const u16* __restrict__ P, const u16* __restrict__ Vt,
    const float* __restrict__ L, float* __restrict__ Out,
    long pStride, int bBase, int zCount)
{
    __shared__ u16 lds[65536];
    const int d = (int)blockIdx.x;            // 0 .. 128*zCount-1
    const int x = d & 7;
    const int q = d >> 3;
    const int spr = zCount << 3;              // slots per round
    const int s = q % spr;
    const int r = q / spr;                    // 0 (big) / 1 (small)
    const int nt = s & 7;
    const int z  = s >> 3;
    const int it = r ? x : 15 - x;
    const int b  = bBase + z;
    const int i0 = it << 8, n0 = nt << 8;

    const u16* Ab = P  + (size_t)z * pStride + (size_t)i0 * 4096;
    const u16* Bb = Vt + (size_t)b * (2048ll * 4096) + (size_t)n0 * 4096;
    f32x4 acc[8][4] = {};
    gemm256_core(Ab, Bb, 4096, 4096, (it + 1) * 4, lds, acc);

    const float* Lb = L + (size_t)b * 4096;
    float* Ob = Out + (size_t)b * (4096ll * 2048);
    const int lane = threadIdx.x & 63;
    const int c = lane & 15, g = lane >> 4;
    const int wid = threadIdx.x >> 6;
    const int rowb = i0 + (wid >> 2) * 128 + g * 4;
    const int colb = n0 + (wid & 3) * 64 + c;
#pragma unroll
    for (int m = 0; m < 8; ++m) {
#pragma unroll
        for (int r2 = 0; r2 < 4; ++r2) {
            const int I = rowb + m * 16 + r2;
            const float inv = 1.0f / Lb[I];
#pragma unroll
            for (int n = 0; n < 4; ++n)
                Ob[(size_t)I * 2048 + colb + n * 16] = acc[m][n][r2] * inv;
        }
    }
}

// ---------------------------------------------------------------------------
// Old 128-tile core (kept for the small Mt GEMM: 2048^2 -> 256 blocks)
// ---------------------------------------------------------------------------
__device__ __forceinline__ void gemm_core_128(
    const u16* __restrict__ A, const u16* __restrict__ Bt,
    int lda, int ldb, int kSteps,
    u16* ldsA, u16* ldsB, f32x4 (&acc)[4][4])
{
    const int tid  = threadIdx.x;
    const int lane = tid & 63;
    const int wr   = (tid >> 7) & 1;
    const int wc   = (tid >> 6) & 1;
    const int g    = lane >> 4;
    const int c    = lane & 15;

    const u16* aSrc = A  + (size_t)(tid >> 3) * lda + (tid & 7) * 8;
    const u16* bSrc = Bt + (size_t)(tid >> 3) * ldb + (tid & 7) * 8;
    u16* aDst = ldsA + tid * 8;
    u16* bDst = ldsB + tid * 8;

    for (int kt = 0; kt < kSteps; ++kt) {
#pragma unroll
        for (int it = 0; it < 4; ++it) {
            gload16(aSrc + (size_t)it * 32 * lda, aDst + it * 2048);
            gload16(bSrc + (size_t)it * 32 * ldb, bDst + it * 2048);
        }
        aSrc += 64; bSrc += 64;
        __syncthreads();
#pragma unroll
        for (int kk = 0; kk < 2; ++kk) {
            s16x8 av[4], bv[4];
#pragma unroll
            for (int m = 0; m < 4; ++m)
                av[m] = *(const s16x8*)(ldsA + (size_t)(wr*64 + m*16 + c) * 64 + kk*32 + g*8);
#pragma unroll
            for (int n = 0; n < 4; ++n)
                bv[n] = *(const s16x8*)(ldsB + (size_t)(wc*64 + n*16 + c) * 64 + kk*32 + g*8);
#pragma unroll
            for (int m = 0; m < 4; ++m)
#pragma unroll
                for (int n = 0; n < 4; ++n)
                    MFMA_BF16(av[m], bv[n], acc[m][n]);
        }
        __syncthreads();
    }
}

__global__ __launch_bounds__(256) void gemm_bt_bf16(
    const u16* __restrict__ A, const u16* __restrict__ Bt, u16* __restrict__ C,
    int N, int K)
{
    __shared__ u16 ldsA[128 * 64];
    __shared__ u16 ldsB[128 * 64];
    const int nT = N >> 7;
    const int m0 = (int)(blockIdx.x / nT) << 7;
    const int n0 = (int)(blockIdx.x % nT) << 7;
    const u16* Ab = A + (size_t)m0 * K;
    const u16* Bb = Bt + (size_t)n0 * K;
    f32x4 acc[4][4] = {};
    gemm_core_128(Ab, Bb, K, K, K >> 6, ldsA, ldsB, acc);

    const int lane = threadIdx.x & 63;
    const int wr = (threadIdx.x >> 7) & 1, wc = (threadIdx.x >> 6) & 1;
    const int rb = m0 + wr * 64 + ((lane >> 4) << 2);
    const int cb = n0 + wc * 64 + (lane & 15);
#pragma unroll
    for (int m = 0; m < 4; ++m)
#pragma unroll
        for (int n = 0; n < 4; ++n)
#pragma unroll
            for (int r = 0; r < 4; ++r)
                C[(size_t)(rb + m*16 + r) * N + cb + n*16] = f2bf(acc[m][n][r]);
}

// ---------------------------------------------------------------------------
// Converters
// ---------------------------------------------------------------------------
__global__ __launch_bounds__(256) void cvt_f32_bf16x8(
    const float* __restrict__ in, u16* __restrict__ out, long n8)
{
    long i = (long)blockIdx.x * 256 + threadIdx.x;
    if (i >= n8) return;
    const float4* p = (const float4*)(in + i * 8);
    float4 v0 = p[0], v1 = p[1];
    u16x8 o;
    o[0] = f2bf(v0.x); o[1] = f2bf(v0.y); o[2] = f2bf(v0.z); o[3] = f2bf(v0.w);
    o[4] = f2bf(v1.x); o[5] = f2bf(v1.y); o[6] = f2bf(v1.z); o[7] = f2bf(v1.w);
    *(u16x8*)(out + i * 8) = o;
}

// W [dim,dim] fp32 -> Wt [dim,dim] bf16 transposed, LDS-tiled 64x64
__global__ __launch_bounds__(256) void transpose_cvt(
    const float* __restrict__ W, u16* __restrict__ Wt, int dim)
{
    __shared__ float tile[64][65];
    const int nb = dim >> 6;
    const int br = blockIdx.x / nb, bc = blockIdx.x % nb;
    const int t  = threadIdx.x;
    const int lr = t >> 2;
    const int lc = (t & 3) << 4;
    const float* src = W + (size_t)(br * 64 + lr) * dim + bc * 64 + lc;
#pragma unroll
    for (int q = 0; q < 4; ++q) {
        float4 v = *(const float4*)(src + q * 4);
        tile[lr][lc + q * 4 + 0] = v.x;
        tile[lr][lc + q * 4 + 1] = v.y;
        tile[lr][lc + q * 4 + 2] = v.z;
        tile[lr][lc + q * 4 + 3] = v.w;
    }
    __syncthreads();
    u16* dst = Wt + (size_t)(bc * 64 + lr) * dim + br * 64 + lc;
    u16x8 o0, o1;
#pragma unroll
    for (int q = 0; q < 8; ++q) o0[q] = f2bf(tile[lc + q][lr]);
#pragma unroll
    for (int q = 0; q < 8; ++q) o1[q] = f2bf(tile[lc + 8 + q][lr]);
    *(u16x8*)(dst)     = o0;
    *(u16x8*)(dst + 8) = o1;
}

__global__ __launch_bounds__(256) void zero_f32(float* p, int n)
{
    int i = blockIdx.x * 256 + threadIdx.x;
    if (i < n) p[i] = 0.0f;
}

// ---------------------------------------------------------------------------
extern "C" void kernel_launch(void* const* d_in, const int* in_sizes, int n_in,
                              void* d_out, int out_size, void* d_ws, size_t ws_size,
                              hipStream_t stream)
{
    const float* x  = (const float*)d_in[0];
    const float* Wq = (const float*)d_in[1];
    const float* Wk = (const float*)d_in[2];
    const float* Wv = (const float*)d_in[3];
    float* out = (float*)d_out;   // reference output dtype is float32

    char* ws = (char*)d_ws;
    u16*   xb  = (u16*)(ws + 0ull);           //  67,108,864  x bf16 [16384,2048]
    u16*   Tm  = (u16*)(ws + 67108864ull);    //  67,108,864  t = x*(WqWk^T)
    u16*   Vt  = (u16*)(ws + 134217728ull);   //  67,108,864  V^T [4][2048][4096]
    u16*   Wqb = (u16*)(ws + 201326592ull);   //   8,388,608
    u16*   Wkb = (u16*)(ws + 209715200ull);   //   8,388,608
    u16*   Wvt = (u16*)(ws + 218103808ull);   //   8,388,608  Wv^T bf16
    u16*   Mt  = (u16*)(ws + 226492416ull);   //   8,388,608  Wk*Wq^T bf16
    float* L   = (float*)(ws + 234881024ull); //      65,536  row sums
    u16*   P   = (u16*)(ws + 234946560ull);   // 134,217,728 (full) / 33,554,432 (per-batch)
    const size_t needBase = 234946560ull;
    const size_t needFull = needBase + 134217728ull;
    const size_t needPerB = needBase + 33554432ull;
    if (ws_size < needPerB) return;

    // 1. converts
    cvt_f32_bf16x8<<<16384, 256, 0, stream>>>(x,  xb,  4194304);
    cvt_f32_bf16x8<<<2048,  256, 0, stream>>>(Wq, Wqb, 524288);
    cvt_f32_bf16x8<<<2048,  256, 0, stream>>>(Wk, Wkb, 524288);
    transpose_cvt <<<1024,  256, 0, stream>>>(Wv, Wvt, 2048);

    // 2. Mt = Wk @ Wq^T (small: keep 128-tile kernel for occupancy)
    gemm_bt_bf16<<<dim3(256, 1, 1), 256, 0, stream>>>(Wkb, Wqb, Mt, 2048, 2048);
    // 3. t = xb @ Mt^T   [16384, 2048]  (64 x 8 = 512 tiles)
    gemm256_bf16<<<dim3(512, 1, 1), 512, 0, stream>>>(xb, Mt, Tm, 2048, 2048, 0, 0, 0);
    // 4. Vt[b] = Wvt @ xb[b]^T  [2048, 4096] per batch (8 x 16 = 128 tiles)
    gemm256_bf16<<<dim3(128, 1, 4), 512, 0, stream>>>(Wvt, xb, Vt, 4096, 2048,
                                                      0, 8388608, 8388608);
    // 5. zero row sums
    zero_f32<<<64, 256, 0, stream>>>(L, 16384);

    // 6/7. scores+exp+rowsum -> P~, then O = (P~ @ V)/l
    if (ws_size >= needFull) {
        attn_score256<<<dim3(136, 1, 4), 512, 0, stream>>>(Tm, xb, P, L, 16777216ll, 0);
        attn_pv256   <<<dim3(512, 1, 1), 512, 0, stream>>>(P, Vt, L, out, 16777216ll, 0, 4);
    } else {
        for (int b = 0; b < 4; ++b) {
            attn_score256<<<dim3(136, 1, 1), 512, 0, stream>>>(Tm, xb, P, L, 0, b);
            attn_pv256   <<<dim3(128, 1, 1), 512, 0, stream>>>(P, Vt, L, out, 0, b, 1);
        }
    }
}

// Round 10
// 621.560 us; speedup vs baseline: 1.1520x; 1.1520x over previous
//
#include <hip/hip_runtime.h>

using u16   = unsigned short;
using s16x8 = __attribute__((ext_vector_type(8))) short;          // 8 bf16 (4 VGPRs)
using u16x8 = __attribute__((ext_vector_type(8))) unsigned short;
using f32x4 = __attribute__((ext_vector_type(4))) float;

// fp32 -> bf16 round-to-nearest-even (bit math, deterministic)
__device__ __forceinline__ u16 f2bf(float f) {
    unsigned u = __float_as_uint(f);
    u += 0x7FFFu + ((u >> 16) & 1u);
    return (u16)(u >> 16);
}

// async global->LDS, 16B per lane; LDS dest must be wave-uniform base + lane*16
__device__ __forceinline__ void gload16(const void* g, void* l) {
    __builtin_amdgcn_global_load_lds((const __attribute__((address_space(1))) void*)g,
                                     (__attribute__((address_space(3))) void*)l, 16, 0, 0);
}

#define MFMA_BF16(a, b, d) \
    d = __builtin_amdgcn_mfma_f32_16x16x32_bf16(a, b, d, 0, 0, 0)

// ---------------------------------------------------------------------------
// 256x256 4-phase GEMM core — ROUND-7 schedule (best measured: 641 us total).
// 512 threads = 8 waves (2M x 4N); per-wave 128x64 = acc[8][4] f32x4. BK=64;
// LDS = 2 x 64 KiB dbuf, XOR-swizzled (byte ^= (row&7)<<4) with linear
// gload_lds dest + pre-swizzled global source col + same XOR on ds_read
// (rule #21 both-sides). Staging 6@P1 + 2@P2 for tile t+1; waits:
// vmcnt(2)@P1-start, vmcnt(8)@P3-start (tile t's A1,A3; ~5-phase cover),
// vmcnt(2)@P4-end (tile t+1's first 6; ~3-phase cover). Never drains to 0
// mid-loop. 4 barriers/K-tile; reads+MFMA inside each super-phase left to
// compiler scheduling (r8 showed more pinning hurts).
// ---------------------------------------------------------------------------
__device__ __forceinline__ void gemm256_core(
    const u16* __restrict__ A, const u16* __restrict__ Bt,
    int lda, int ldb, int kSteps, u16* lds, f32x4 (&acc)[8][4])
{
    const int tid  = threadIdx.x;
    const int lane = tid & 63;
    const int wid  = tid >> 6;
    const int wr   = wid >> 2;      // 0..1  (M half)
    const int wc   = wid & 3;       // 0..3  (N quarter)
    const int c    = lane & 15;
    const int g    = lane >> 4;

    // staging: thread t -> physical LDS sweep s: s*8192B + tid*16B (linear).
    // logical element = physical ^ ((row&7)<<4) => fetch global at swizzled col
    const int srow = tid >> 3;                               // row in 64-row sweep
    const int scol = ((tid & 7) * 8) ^ ((srow & 7) << 3);    // u16 units
    const u16* pA = A  + (size_t)srow * lda + scol;
    const u16* pB = Bt + (size_t)srow * ldb + scol;
    const size_t sA = (size_t)64 * lda;
    const size_t sB = (size_t)64 * ldb;
    const int ldst = tid * 8;                                // u16 within segment

    // read-side offsets (swizzle folds to lane-constant XOR)
    const int low0 = (g * 8)      ^ ((c & 7) << 3);          // kk=0, u16 units
    const int low1 = (32 + g * 8) ^ ((c & 7) << 3);          // kk=1
    const int aRow = (wr * 128 + c) * 64;                    // + m*1024
    const int bRow = (wc * 64 + c) * 64;                     // + n*1024

    // prologue: tile0 into buf0, order {A0,A2,B0..B3},{A1,A3}
    {
        u16* wA = lds;
        u16* wB = lds + 16384;
        gload16(pA + 0 * sA, wA + 0 * 4096 + ldst);
        gload16(pA + 2 * sA, wA + 2 * 4096 + ldst);
        gload16(pB + 0 * sB, wB + 0 * 4096 + ldst);
        gload16(pB + 1 * sB, wB + 1 * 4096 + ldst);
        gload16(pB + 2 * sB, wB + 2 * 4096 + ldst);
        gload16(pB + 3 * sB, wB + 3 * 4096 + ldst);
        gload16(pA + 1 * sA, wA + 1 * 4096 + ldst);
        gload16(pA + 3 * sA, wA + 3 * 4096 + ldst);
    }
    if (kSteps > 1) { pA += 64; pB += 64; }

    for (int t = 0; t < kSteps; ++t) {
        const u16* rdA = lds + (t & 1) * 32768;
        const u16* rdB = rdA + 16384;
        u16* wA = lds + ((t & 1) ^ 1) * 32768;
        u16* wB = wA + 16384;
        const bool more = (t + 1 < kSteps);

        s16x8 av[4][2], bv[2][2], bw[2][2];

        // ---- P1: quadrant (m0..3, n0..1); issue next {A0,A2,B0..B3} ----
        asm volatile("s_waitcnt vmcnt(2)" ::: "memory");
        __builtin_amdgcn_s_barrier();
        __builtin_amdgcn_sched_barrier(0);
        if (more) {
            gload16(pA + 0 * sA, wA + 0 * 4096 + ldst);
            gload16(pA + 2 * sA, wA + 2 * 4096 + ldst);
            gload16(pB + 0 * sB, wB + 0 * 4096 + ldst);
            gload16(pB + 1 * sB, wB + 1 * 4096 + ldst);
            gload16(pB + 2 * sB, wB + 2 * 4096 + ldst);
            gload16(pB + 3 * sB, wB + 3 * 4096 + ldst);
        }
#pragma unroll
        for (int m = 0; m < 4; ++m) {
            av[m][0] = *(const s16x8*)(rdA + aRow + m * 1024 + low0);
            av[m][1] = *(const s16x8*)(rdA + aRow + m * 1024 + low1);
        }
#pragma unroll
        for (int n = 0; n < 2; ++n) {
            bv[n][0] = *(const s16x8*)(rdB + bRow + n * 1024 + low0);
            bv[n][1] = *(const s16x8*)(rdB + bRow + n * 1024 + low1);
        }
        __builtin_amdgcn_s_setprio(1);
#pragma unroll
        for (int m = 0; m < 4; ++m)
#pragma unroll
            for (int n = 0; n < 2; ++n) {
                MFMA_BF16(av[m][0], bv[n][0], acc[m][n]);
                MFMA_BF16(av[m][1], bv[n][1], acc[m][n]);
            }
        __builtin_amdgcn_s_setprio(0);
        __builtin_amdgcn_s_barrier();

        // ---- P2: quadrant (m0..3, n2..3); issue next {A1,A3} ----
#pragma unroll
        for (int n = 0; n < 2; ++n) {
            bw[n][0] = *(const s16x8*)(rdB + bRow + (n + 2) * 1024 + low0);
            bw[n][1] = *(const s16x8*)(rdB + bRow + (n + 2) * 1024 + low1);
        }
        if (more) {
            gload16(pA + 1 * sA, wA + 1 * 4096 + ldst);
            gload16(pA + 3 * sA, wA + 3 * 4096 + ldst);
        }
        __builtin_amdgcn_s_setprio(1);
#pragma unroll
        for (int m = 0; m < 4; ++m)
#pragma unroll
            for (int n = 0; n < 2; ++n) {
                MFMA_BF16(av[m][0], bw[n][0], acc[m][n + 2]);
                MFMA_BF16(av[m][1], bw[n][1], acc[m][n + 2]);
            }
        __builtin_amdgcn_s_setprio(0);

        // ---- P3: quadrant (m4..7, n2..3); drain tile t's A1,A3 ----
        if (more) asm volatile("s_waitcnt vmcnt(8)" ::: "memory");
        else      asm volatile("s_waitcnt vmcnt(0)" ::: "memory");
        __builtin_amdgcn_s_barrier();
        __builtin_amdgcn_sched_barrier(0);
#pragma unroll
        for (int m = 0; m < 4; ++m) {
            av[m][0] = *(const s16x8*)(rdA + aRow + (m + 4) * 1024 + low0);
            av[m][1] = *(const s16x8*)(rdA + aRow + (m + 4) * 1024 + low1);
        }
        __builtin_amdgcn_s_setprio(1);
#pragma unroll
        for (int m = 0; m < 4; ++m)
#pragma unroll
            for (int n = 0; n < 2; ++n) {
                MFMA_BF16(av[m][0], bw[n][0], acc[m + 4][n + 2]);
                MFMA_BF16(av[m][1], bw[n][1], acc[m + 4][n + 2]);
            }
        __builtin_amdgcn_s_setprio(0);
        __builtin_amdgcn_s_barrier();

        // ---- P4: quadrant (m4..7, n0..1) ----
        __builtin_amdgcn_s_setprio(1);
#pragma unroll
        for (int m = 0; m < 4; ++m)
#pragma unroll
            for (int n = 0; n < 2; ++n) {
                MFMA_BF16(av[m][0], bv[n][0], acc[m + 4][n]);
                MFMA_BF16(av[m][1], bv[n][1], acc[m + 4][n]);
            }
        __builtin_amdgcn_s_setprio(0);
        if (more) asm volatile("s_waitcnt vmcnt(2)" ::: "memory");
        __builtin_amdgcn_s_barrier();

        if (t + 2 < kSteps) { pA += 64; pB += 64; }
    }
    asm volatile("s_waitcnt vmcnt(0)" ::: "memory");
}

// bijective XCD swizzle (requires nwg % 8 == 0; all our grids satisfy this)
__device__ __forceinline__ int xcd_swz(int bid, int nwg) {
    return (bid & 7) * (nwg >> 3) + (bid >> 3);
}

// ---------------------------------------------------------------------------
// 256-tile GEMM, bf16 output (Tm, Vt). grid.x = (M/256)*(N/256), grid.z = batch
// ---------------------------------------------------------------------------
__global__ __launch_bounds__(512, 2) void gemm256_bf16(
    const u16* __restrict__ A, const u16* __restrict__ Bt, u16* __restrict__ C,
    int N, int K, long aBatch, long bBatch, long cBatch)
{
    __shared__ u16 lds[65536];
    const int bid = xcd_swz((int)blockIdx.x, (int)gridDim.x);
    const int nT = N >> 8;
    const int m0 = (bid / nT) << 8;
    const int n0 = (bid % nT) << 8;
    const int b  = blockIdx.z;
    const u16* Ab = A  + (size_t)b * aBatch + (size_t)m0 * K;
    const u16* Bb = Bt + (size_t)b * bBatch + (size_t)n0 * K;
    f32x4 acc[8][4] = {};
    gemm256_core(Ab, Bb, K, K, K >> 6, lds, acc);

    u16* Cb = C + (size_t)b * cBatch;
    const int lane = threadIdx.x & 63;
    const int c = lane & 15, g = lane >> 4;
    const int wid = threadIdx.x >> 6;
    const int rowb = m0 + (wid >> 2) * 128 + g * 4;
    const int colb = n0 + (wid & 3) * 64 + c;
#pragma unroll
    for (int m = 0; m < 8; ++m)
#pragma unroll
        for (int n = 0; n < 4; ++n)
#pragma unroll
            for (int r = 0; r < 4; ++r)
                Cb[(size_t)(rowb + m * 16 + r) * N + colb + n * 16] = f2bf(acc[m][n][r]);
}

// ---------------------------------------------------------------------------
// attn_score 256: P~ = exp(scale * t . x^T) on causal lower-triangle 256-tiles;
// row sums via shfl reduce + atomicAdd. grid.x = 136, grid.z = batch.
// ---------------------------------------------------------------------------
__global__ __launch_bounds__(512, 2) void attn_score256(
    const u16* __restrict__ Tm, const u16* __restrict__ Xb,
    u16* __restrict__ P, float* __restrict__ L, long pStride, int bBase)
{
    __shared__ u16 lds[65536];
    const int b  = bBase + blockIdx.z;
    const int wg = xcd_swz((int)blockIdx.x, (int)gridDim.x);   // 136 = 8*17
    int it = (int)((sqrtf(8.0f * (float)wg + 1.0f) - 1.0f) * 0.5f);
    while ((it + 1) * (it + 2) / 2 <= wg) ++it;
    while (it * (it + 1) / 2 > wg) --it;
    const int jt = wg - it * (it + 1) / 2;
    const int i0 = it << 8, j0 = jt << 8;

    const u16* Ab = Tm + ((size_t)b * 4096 + i0) * 2048;
    const u16* Bb = Xb + ((size_t)b * 4096 + j0) * 2048;
    f32x4 acc[8][4] = {};
    gemm256_core(Ab, Bb, 2048, 2048, 32, lds, acc);

    u16*   Pb = P + (size_t)blockIdx.z * pStride;
    float* Lb = L + (size_t)b * 4096;
    const int lane = threadIdx.x & 63;
    const int c = lane & 15, g = lane >> 4;
    const int wid = threadIdx.x >> 6;
    const int rowb = i0 + (wid >> 2) * 128 + g * 4;
    const int colb = j0 + (wid & 3) * 64 + c;
    const float SCALE = 0.022097086912079608f;   // 1/sqrt(2048)

    float rsum[8][4];
#pragma unroll
    for (int m = 0; m < 8; ++m)
#pragma unroll
        for (int r = 0; r < 4; ++r) rsum[m][r] = 0.0f;
#pragma unroll
    for (int m = 0; m < 8; ++m) {
#pragma unroll
        for (int r = 0; r < 4; ++r) {
            const int Ig = rowb + m * 16 + r;
#pragma unroll
            for (int n = 0; n < 4; ++n) {
                const int Jg = colb + n * 16;
                // scaled scores ~N(0,0.82^2) => unnormalized exp is safe
                float p = (Jg > Ig) ? 0.0f : __expf(acc[m][n][r] * SCALE);
                Pb[(size_t)Ig * 4096 + Jg] = f2bf(p);
                rsum[m][r] += p;
            }
        }
    }
    // reduce across the 16 c-lanes (masks <16 stay within the g-group = same rows)
#pragma unroll
    for (int m = 0; m < 8; ++m)
#pragma unroll
        for (int r = 0; r < 4; ++r) {
            float v = rsum[m][r];
            v += __shfl_xor(v, 1);
            v += __shfl_xor(v, 2);
            v += __shfl_xor(v, 4);
            v += __shfl_xor(v, 8);
            rsum[m][r] = v;
        }
    if (c == 0) {
#pragma unroll
        for (int m = 0; m < 8; ++m)
#pragma unroll
            for (int r = 0; r < 4; ++r)
                atomicAdd(&Lb[rowb + m * 16 + r], rsum[m][r]);
    }
}

// ---------------------------------------------------------------------------
// attn_pv 256: O = (P~ @ V)/l over causal K-range; f32 output.
// Flat grid with explicit balance map: d -> (x = d&7, round r, slot s).
// it = r ? x : 15-x  => each CU gets it and 15-it => uniform 68 K-steps/CU.
// ---------------------------------------------------------------------------
__global__ __launch_bounds__(512, 2) void attn_pv256(
    const u16* __restrict__ P, const u16* __restrict__ Vt,
    const float* __restrict__ L, float* __restrict__ Out,
    long pStride, int bBase, int zCount)
{
    __shared__ u16 lds[65536];
    const int d = (int)blockIdx.x;            // 0 .. 128*zCount-1
    const int x = d & 7;
    const int q = d >> 3;
    const int spr = zCount << 3;              // slots per round
    const int s = q % spr;
    const int r = q / spr;                    // 0 (big) / 1 (small)
    const int nt = s & 7;
    const int z  = s >> 3;
    const int it = r ? x : 15 - x;
    const int b  = bBase + z;
    const int i0 = it << 8, n0 = nt << 8;

    const u16* Ab = P  + (size_t)z * pStride + (size_t)i0 * 4096;
    const u16* Bb = Vt + (size_t)b * (2048ll * 4096) + (size_t)n0 * 4096;
    f32x4 acc[8][4] = {};
    gemm256_core(Ab, Bb, 4096, 4096, (it + 1) * 4, lds, acc);

    const float* Lb = L + (size_t)b * 4096;
    float* Ob = Out + (size_t)b * (4096ll * 2048);
    const int lane = threadIdx.x & 63;
    const int c = lane & 15, g = lane >> 4;
    const int wid = threadIdx.x >> 6;
    const int rowb = i0 + (wid >> 2) * 128 + g * 4;
    const int colb = n0 + (wid & 3) * 64 + c;
#pragma unroll
    for (int m = 0; m < 8; ++m) {
#pragma unroll
        for (int r2 = 0; r2 < 4; ++r2) {
            const int I = rowb + m * 16 + r2;
            const float inv = 1.0f / Lb[I];
#pragma unroll
            for (int n = 0; n < 4; ++n)
                Ob[(size_t)I * 2048 + colb + n * 16] = acc[m][n][r2] * inv;
        }
    }
}

// ---------------------------------------------------------------------------
// 128-tile core (Mt GEMM inside fused_prep)
// ---------------------------------------------------------------------------
__device__ __forceinline__ void gemm_core_128(
    const u16* __restrict__ A, const u16* __restrict__ Bt,
    int lda, int ldb, int kSteps,
    u16* ldsA, u16* ldsB, f32x4 (&acc)[4][4])
{
    const int tid  = threadIdx.x;
    const int lane = tid & 63;
    const int wr   = (tid >> 7) & 1;
    const int wc   = (tid >> 6) & 1;
    const int g    = lane >> 4;
    const int c    = lane & 15;

    const u16* aSrc = A  + (size_t)(tid >> 3) * lda + (tid & 7) * 8;
    const u16* bSrc = Bt + (size_t)(tid >> 3) * ldb + (tid & 7) * 8;
    u16* aDst = ldsA + tid * 8;
    u16* bDst = ldsB + tid * 8;

    for (int kt = 0; kt < kSteps; ++kt) {
#pragma unroll
        for (int it = 0; it < 4; ++it) {
            gload16(aSrc + (size_t)it * 32 * lda, aDst + it * 2048);
            gload16(bSrc + (size_t)it * 32 * ldb, bDst + it * 2048);
        }
        aSrc += 64; bSrc += 64;
        __syncthreads();
#pragma unroll
        for (int kk = 0; kk < 2; ++kk) {
            s16x8 av[4], bv[4];
#pragma unroll
            for (int m = 0; m < 4; ++m)
                av[m] = *(const s16x8*)(ldsA + (size_t)(wr*64 + m*16 + c) * 64 + kk*32 + g*8);
#pragma unroll
            for (int n = 0; n < 4; ++n)
                bv[n] = *(const s16x8*)(ldsB + (size_t)(wc*64 + n*16 + c) * 64 + kk*32 + g*8);
#pragma unroll
            for (int m = 0; m < 4; ++m)
#pragma unroll
                for (int n = 0; n < 4; ++n)
                    MFMA_BF16(av[m], bv[n], acc[m][n]);
        }
        __syncthreads();
    }
}

// ---------------------------------------------------------------------------
// cvt_w2: Wq and Wk fp32 -> bf16 in one kernel. grid 4096 x 256.
// ---------------------------------------------------------------------------
__global__ __launch_bounds__(256) void cvt_w2(
    const float* __restrict__ Wq, const float* __restrict__ Wk,
    u16* __restrict__ Wqb, u16* __restrict__ Wkb)
{
    int bid = (int)blockIdx.x;
    const float* src; u16* dst;
    if (bid < 2048) { src = Wq; dst = Wqb; }
    else            { src = Wk; dst = Wkb; bid -= 2048; }
    long i = (long)bid * 256 + threadIdx.x;          // < 524288; x8 elems
    const float4* p = (const float4*)(src + i * 8);
    float4 v0 = p[0], v1 = p[1];
    u16x8 o;
    o[0] = f2bf(v0.x); o[1] = f2bf(v0.y); o[2] = f2bf(v0.z); o[3] = f2bf(v0.w);
    o[4] = f2bf(v1.x); o[5] = f2bf(v1.y); o[6] = f2bf(v1.z); o[7] = f2bf(v1.w);
    *(u16x8*)(dst + i * 8) = o;
}

// ---------------------------------------------------------------------------
// fused_prep: heterogeneous kernel overlapping MFMA-only Mt GEMM with the
// BW-only converts (m114: MFMA and VMEM/VALU pipes co-schedule across blocks).
//   bid [0,256):      Mt = Wkb @ Wqb^T  (128^2 tiles, K=2048)
//   bid [256,2304):   x fp32 -> bf16 (8-step grid-stride, 16B loads)
//   bid [2304,3328):  Wv transpose+convert (64x64 LDS tiles)
//   bid [3328,3392):  zero L
// Heavy blocks first in dispatch order. 32 KB shared LDS, aliased per role.
// ---------------------------------------------------------------------------
__global__ __launch_bounds__(256) void fused_prep(
    const float* __restrict__ x, const float* __restrict__ Wv,
    const u16* __restrict__ Wqb, const u16* __restrict__ Wkb,
    u16* __restrict__ xb, u16* __restrict__ Wvt, u16* __restrict__ Mt,
    float* __restrict__ L)
{
    __shared__ __align__(16) u16 smem[16384];   // 32 KB
    const int bid = (int)blockIdx.x;
    const int t   = threadIdx.x;

    if (bid < 256) {
        // ---- Mt GEMM: 16x16 grid of 128^2 tiles, N=K=2048 ----
        const int m0 = (bid >> 4) << 7;
        const int n0 = (bid & 15) << 7;
        f32x4 acc[4][4] = {};
        gemm_core_128(Wkb + (size_t)m0 * 2048, Wqb + (size_t)n0 * 2048,
                      2048, 2048, 32, smem, smem + 8192, acc);
        const int lane = t & 63;
        const int wr = (t >> 7) & 1, wc = (t >> 6) & 1;
        const int rb = m0 + wr * 64 + ((lane >> 4) << 2);
        const int cb = n0 + wc * 64 + (lane & 15);
#pragma unroll
        for (int m = 0; m < 4; ++m)
#pragma unroll
            for (int n = 0; n < 4; ++n)
#pragma unroll
                for (int r = 0; r < 4; ++r)
                    Mt[(size_t)(rb + m*16 + r) * 2048 + cb + n*16] = f2bf(acc[m][n][r]);
    } else if (bid < 2304) {
        // ---- x convert: 2048 blocks x 256 thr x 8 strides x 8 elems ----
        const long base = (long)(bid - 256) * 256 + t;      // < 524288
#pragma unroll
        for (int k = 0; k < 8; ++k) {
            const long i = base + (long)k * 524288;         // < 4194304
            const float4* p = (const float4*)(x + i * 8);
            float4 v0 = p[0], v1 = p[1];
            u16x8 o;
            o[0] = f2bf(v0.x); o[1] = f2bf(v0.y); o[2] = f2bf(v0.z); o[3] = f2bf(v0.w);
            o[4] = f2bf(v1.x); o[5] = f2bf(v1.y); o[6] = f2bf(v1.z); o[7] = f2bf(v1.w);
            *(u16x8*)(xb + i * 8) = o;
        }
    } else if (bid < 3328) {
        // ---- Wv transpose+convert: 32x32 grid of 64x64 tiles ----
        float (*tile)[65] = (float (*)[65])smem;            // 16.6 KB <= 32 KB
        const int wbid = bid - 2304;
        const int br = wbid >> 5, bc = wbid & 31;
        const int lr = t >> 2;
        const int lc = (t & 3) << 4;
        const float* src = Wv + (size_t)(br * 64 + lr) * 2048 + bc * 64 + lc;
#pragma unroll
        for (int q = 0; q < 4; ++q) {
            float4 v = *(const float4*)(src + q * 4);
            tile[lr][lc + q * 4 + 0] = v.x;
            tile[lr][lc + q * 4 + 1] = v.y;
            tile[lr][lc + q * 4 + 2] = v.z;
            tile[lr][lc + q * 4 + 3] = v.w;
        }
        __syncthreads();
        u16* dst = Wvt + (size_t)(bc * 64 + lr) * 2048 + br * 64 + lc;
        u16x8 o0, o1;
#pragma unroll
        for (int q = 0; q < 8; ++q) o0[q] = f2bf(tile[lc + q][lr]);
#pragma unroll
        for (int q = 0; q < 8; ++q) o1[q] = f2bf(tile[lc + 8 + q][lr]);
        *(u16x8*)(dst)     = o0;
        *(u16x8*)(dst + 8) = o1;
    } else {
        // ---- zero L (16384 floats) ----
        const int i = (bid - 3328) * 256 + t;
        if (i < 16384) L[i] = 0.0f;
    }
}

// ---------------------------------------------------------------------------
extern "C" void kernel_launch(void* const* d_in, const int* in_sizes, int n_in,
                              void* d_out, int out_size, void* d_ws, size_t ws_size,
                              hipStream_t stream)
{
    const float* x  = (const float*)d_in[0];
    const float* Wq = (const float*)d_in[1];
    const float* Wk = (const float*)d_in[2];
    const float* Wv = (const float*)d_in[3];
    float* out = (float*)d_out;   // reference output dtype is float32

    char* ws = (char*)d_ws;
    u16*   xb  = (u16*)(ws + 0ull);           //  67,108,864  x bf16 [16384,2048]
    u16*   Tm  = (u16*)(ws + 67108864ull);    //  67,108,864  t = x*(WqWk^T)
    u16*   Vt  = (u16*)(ws + 134217728ull);   //  67,108,864  V^T [4][2048][4096]
    u16*   Wqb = (u16*)(ws + 201326592ull);   //   8,388,608
    u16*   Wkb = (u16*)(ws + 209715200ull);   //   8,388,608
    u16*   Wvt = (u16*)(ws + 218103808ull);   //   8,388,608  Wv^T bf16
    u16*   Mt  = (u16*)(ws + 226492416ull);   //   8,388,608  Wk*Wq^T bf16
    float* L   = (float*)(ws + 234881024ull); //      65,536  row sums
    u16*   P   = (u16*)(ws + 234946560ull);   // 134,217,728 (full) / 33,554,432 (per-batch)
    const size_t needBase = 234946560ull;
    const size_t needFull = needBase + 134217728ull;
    const size_t needPerB = needBase + 33554432ull;
    if (ws_size < needPerB) return;

    // 1. Wq/Wk converts (Mt depends on them)
    cvt_w2<<<4096, 256, 0, stream>>>(Wq, Wk, Wqb, Wkb);
    // 2. fused prep: Mt GEMM overlapped with x-convert, Wv-transpose, L-zero
    fused_prep<<<3392, 256, 0, stream>>>(x, Wv, Wqb, Wkb, xb, Wvt, Mt, L);

    // 3. t = xb @ Mt^T   [16384, 2048]  (64 x 8 = 512 tiles)
    gemm256_bf16<<<dim3(512, 1, 1), 512, 0, stream>>>(xb, Mt, Tm, 2048, 2048, 0, 0, 0);
    // 4. Vt[b] = Wvt @ xb[b]^T  [2048, 4096] per batch (8 x 16 = 128 tiles)
    gemm256_bf16<<<dim3(128, 1, 4), 512, 0, stream>>>(Wvt, xb, Vt, 4096, 2048,
                                                      0, 8388608, 8388608);

    // 5/6. scores+exp+rowsum -> P~, then O = (P~ @ V)/l
    if (ws_size >= needFull) {
        attn_score256<<<dim3(136, 1, 4), 512, 0, stream>>>(Tm, xb, P, L, 16777216ll, 0);
        attn_pv256   <<<dim3(512, 1, 1), 512, 0, stream>>>(P, Vt, L, out, 16777216ll, 0, 4);
    } else {
        for (int b = 0; b < 4; ++b) {
            attn_score256<<<dim3(136, 1, 1), 512, 0, stream>>>(Tm, xb, P, L, 0, b);
            attn_pv256   <<<dim3(128, 1, 1), 512, 0, stream>>>(P, Vt, L, out, 0, b, 1);
        }
    }
}